// Round 1
// baseline (398.859 us; speedup 1.0000x reference)
//
#include <hip/hip_runtime.h>

#define EMB 128
#define NBUC 1024          // coarse buckets: dst >> 7 (128 nodes per bucket)
#define NPART 256          // partition blocks for P1/P2
#define NSLOT 8            // dim-slices of 16 dims each, one per XCD

typedef __attribute__((ext_vector_type(8))) short short8;   // 8 bf16 (4 VGPRs)
typedef __attribute__((ext_vector_type(4))) float f32x4;    // MFMA acc

// ---------------- bf16 helpers ----------------
__device__ __forceinline__ unsigned short f2bf(float f) {
    union { float f; unsigned int i; } v; v.f = f;
    unsigned int x = v.i;
    x += 0x7fffu + ((x >> 16) & 1u);   // round-to-nearest-even
    return (unsigned short)(x >> 16);
}
__device__ __forceinline__ void acc_bf8(uint4 v, float a[8]) {
    union { unsigned int i; float f; } t;
    t.i = v.x << 16;          a[0] += t.f;
    t.i = v.x & 0xffff0000u;  a[1] += t.f;
    t.i = v.y << 16;          a[2] += t.f;
    t.i = v.y & 0xffff0000u;  a[3] += t.f;
    t.i = v.z << 16;          a[4] += t.f;
    t.i = v.z & 0xffff0000u;  a[5] += t.f;
    t.i = v.w << 16;          a[6] += t.f;
    t.i = v.w & 0xffff0000u;  a[7] += t.f;
}

// ============ CSR build: atomic-light two-level counting sort ============

__global__ __launch_bounds__(256) void p1_hist(const int* __restrict__ dst,
                                               int* __restrict__ BH, int E, int chunk) {
    __shared__ int h[NBUC];
    for (int i = threadIdx.x; i < NBUC; i += 256) h[i] = 0;
    __syncthreads();
    int s = blockIdx.x * chunk;
    int e = min(E, s + chunk);
    for (int i = s + threadIdx.x; i < e; i += 256)
        atomicAdd(&h[dst[i] >> 7], 1);
    __syncthreads();
    for (int i = threadIdx.x; i < NBUC; i += 256)
        BH[blockIdx.x * NBUC + i] = h[i];
}

__global__ __launch_bounds__(256) void p_tot(const int* __restrict__ BH,
                                             int* __restrict__ tot) {
    int b = blockIdx.x * 256 + threadIdx.x;
    int s = 0;
    for (int blk = 0; blk < NPART; ++blk) s += BH[blk * NBUC + b];
    tot[b] = s;
}

__global__ __launch_bounds__(1024) void p_scan(const int* __restrict__ tot,
                                               int* __restrict__ base, int E) {
    __shared__ int a[NBUC];
    int t = threadIdx.x;
    int v0 = tot[t];
    a[t] = v0;
    __syncthreads();
    for (int off = 1; off < NBUC; off <<= 1) {
        int v = (t >= off) ? a[t - off] : 0;
        __syncthreads();
        a[t] += v;
        __syncthreads();
    }
    base[t] = a[t] - v0;
    if (t == NBUC - 1) base[NBUC] = E;
}

__global__ __launch_bounds__(256) void p_offs(int* __restrict__ BH,
                                              const int* __restrict__ base) {
    int b = blockIdx.x * 256 + threadIdx.x;
    int run = base[b];
    for (int blk = 0; blk < NPART; ++blk) {
        int* p = &BH[blk * NBUC + b];
        int v = *p;
        *p = run;
        run += v;
    }
}

__global__ __launch_bounds__(256) void p2_scatter(const int* __restrict__ src,
                                                  const int* __restrict__ dst,
                                                  const int* __restrict__ BH,
                                                  int* __restrict__ part,
                                                  int E, int chunk) {
    __shared__ int cnt[NBUC];
    for (int i = threadIdx.x; i < NBUC; i += 256)
        cnt[i] = BH[blockIdx.x * NBUC + i];
    __syncthreads();
    int s = blockIdx.x * chunk;
    int e = min(E, s + chunk);
    for (int i = s + threadIdx.x; i < e; i += 256) {
        int d = dst[i];
        int pos = atomicAdd(&cnt[d >> 7], 1);
        part[pos] = src[i] | ((d & 127) << 17);   // src < 2^17, local node in [0,128)
    }
}

__global__ __launch_bounds__(256) void p3_csr(const int* __restrict__ part,
                                              const int* __restrict__ base,
                                              int* __restrict__ R, int* __restrict__ adj,
                                              float* __restrict__ dis, int N, int E) {
    __shared__ int hist[128];
    __shared__ int sc[128];
    __shared__ int cnt[128];
    int b = blockIdx.x;
    int n0 = b * 128;
    int nn = min(128, N - n0);
    int s = base[b], e = base[b + 1];
    int t = threadIdx.x;

    if (t < 128) hist[t] = 0;
    __syncthreads();
    for (int i = s + t; i < e; i += 256)
        atomicAdd(&hist[part[i] >> 17], 1);
    __syncthreads();

    if (t < 128) sc[t] = hist[t];
    __syncthreads();
    for (int off = 1; off < 128; off <<= 1) {
        int v = 0;
        if (t < 128 && t >= off) v = sc[t - off];
        __syncthreads();
        if (t < 128) sc[t] += v;
        __syncthreads();
    }
    if (t < 128) {
        int excl = sc[t] - hist[t];
        cnt[t] = excl;
        if (t < nn) {
            R[n0 + t] = s + excl;
            dis[n0 + t] = rsqrtf((float)hist[t] + 1.0f);   // +1 self-loop
        }
    }
    if (b == 0 && t == 0) R[N] = E;
    __syncthreads();

    for (int i = s + t; i < e; i += 256) {
        int p = part[i];
        int pos = atomicAdd(&cnt[p >> 17], 1);
        adj[s + pos] = p & 0x1FFFF;
    }
}

// ---------------- W pre-swizzle: f32 [128][128] -> bf16 fragment order ----------------
// Wb[kk][ct][q][nn][j] = W[kk*32 + q*8 + j][ct*16 + nn]; lane (q*16+nn) then reads
// its B-frag for (kk,ct) as one contiguous 16B short8 at index (kk*8+ct)*64 + lane.
__global__ __launch_bounds__(256) void k_prep_w(const float* __restrict__ W,
                                                unsigned short* __restrict__ Ws) {
    int idx = blockIdx.x * 256 + threadIdx.x;     // 64 blocks x 256 = 16384
    int k = idx >> 7, n = idx & 127;
    int kk = k >> 5, q = (k >> 3) & 3, j = k & 7;
    int ct = n >> 4, nn = n & 15;
    int didx = ((((kk * 8 + ct) * 4 + q) * 16 + nn) << 3) + j;
    Ws[didx] = f2bf(W[idx]);
}

// ---------------- MFMA GEMM: Yb = bf16((X @ W) * dis), SLOT-BLOCKED output ----------
// Output layout: Yb[slot][node][16] bf16, slot = dim/16.  One 3.2MB slot fits a
// single XCD's 4MB L2, which the gather exploits via blockIdx%8 -> XCD pinning.
// 64 nodes/block, 16/wave; K=128 as 4 steps of mfma_f32_16x16x32_bf16.
// Fragment maps (doc-verified): A: m=lane&15, k=q*8+j; B: n=lane&15, k=q*8+j;
// D: n=lane&15, m=q*4+reg.
// In-place safe for layer 2 (X==Y): a block touches only its own 64 rows (the
// last-block clamp arc=N-1 stays inside the last block); all A-frag reads happen
// before the __syncthreads() that precedes any store.
template <bool XBF16>   // true: X is slot-blocked bf16; false: X is row-major f32
__global__ __launch_bounds__(256) void k_gemm_mfma(
    const void* Xv, const unsigned short* __restrict__ Wsw,
    const float* __restrict__ dis, unsigned short* Y, int N)
{
    __shared__ __align__(16) unsigned short lds[16384];   // 32 KB: W frags, then out-stage

    // stage swizzled W (coalesced 16B copies)
    {
        const uint4* srcp = (const uint4*)Wsw;
        uint4* dstp = (uint4*)lds;
        for (int i = threadIdx.x; i < 2048; i += 256) dstp[i] = srcp[i];
    }
    __syncthreads();

    const int wave = threadIdx.x >> 6;
    const int lane = threadIdx.x & 63;
    const int q = lane >> 4, nn = lane & 15;
    const int row0 = blockIdx.x * 64 + wave * 16;
    const int arow = row0 + nn;
    const int arc = arow < N ? arow : N - 1;

    f32x4 acc[8];
#pragma unroll
    for (int ct = 0; ct < 8; ++ct) acc[ct] = (f32x4){0.f, 0.f, 0.f, 0.f};

#pragma unroll
    for (int kk = 0; kk < 4; ++kk) {
        short8 af;
        if (XBF16) {
            // dims kk*32 + q*8 .. +8  ->  slot = kk*2 + (q>>1), offset (q&1)*8
            const int slot = kk * 2 + (q >> 1);
            const int off = (q & 1) * 8;
            af = *(const short8*)((const unsigned short*)Xv +
                                  ((size_t)slot * N + arc) * 16 + off);
        } else {
            const float* xp = (const float*)Xv + (size_t)arc * EMB + kk * 32 + q * 8;
            float4 u0 = *(const float4*)xp;
            float4 u1 = *(const float4*)(xp + 4);
            af[0] = (short)f2bf(u0.x); af[1] = (short)f2bf(u0.y);
            af[2] = (short)f2bf(u0.z); af[3] = (short)f2bf(u0.w);
            af[4] = (short)f2bf(u1.x); af[5] = (short)f2bf(u1.y);
            af[6] = (short)f2bf(u1.z); af[7] = (short)f2bf(u1.w);
        }
#pragma unroll
        for (int ct = 0; ct < 8; ++ct) {
            short8 bf = ((const short8*)lds)[(kk * 8 + ct) * 64 + lane];
            acc[ct] = __builtin_amdgcn_mfma_f32_16x16x32_bf16(af, bf, acc[ct], 0, 0, 0);
        }
    }

    __syncthreads();   // W reads + all A-frag (X) reads complete block-wide

    // scale by dis, pack bf16, stage to LDS (stride 136 shorts = 272B, 16B-aligned)
    float dv[4];
#pragma unroll
    for (int r = 0; r < 4; ++r) {
        int gm = row0 + q * 4 + r;
        dv[r] = dis[gm < N ? gm : N - 1];
    }
#pragma unroll
    for (int ct = 0; ct < 8; ++ct) {
#pragma unroll
        for (int r = 0; r < 4; ++r) {
            int ml = wave * 16 + q * 4 + r;
            lds[ml * 136 + ct * 16 + nn] = f2bf(acc[ct][r] * dv[r]);
        }
    }
    __syncthreads();

    // blocked store: per slot, 64 consecutive node-slices = 2KB contiguous
    const int rbase = blockIdx.x * 64;
    for (int i = threadIdx.x; i < 1024; i += 256) {
        int slot = i >> 7, r2 = (i >> 1) & 63, off = (i & 1) * 8;
        int grow = rbase + r2;
        if (grow < N) {
            uint4 v = *(const uint4*)(lds + r2 * 136 + slot * 16 + off);
            *(uint4*)(Y + ((size_t)slot * N + grow) * 16 + off) = v;
        }
    }
}

// ---------------- gather + normalize + bias (+relu), XCD dim-sharded -------------
// Block = (chunk of 128 nodes) x (1 dim-slot).  slot = blockIdx.x & 7: hardware
// round-robins blockIdx over the 8 XCDs, so every block on XCD s works on the
// SAME 3.2MB slice Yb[s][*][16], which stays resident in that XCD's 4MB L2.
// Per node-slot: 2 threads x uint4 (8 bf16 each).  adj/R are re-read once per
// slot (8x, streaming) -- cheap vs. the random-row L2 misses this removes.
template <bool RELU, bool BF16OUT>
__global__ __launch_bounds__(256) void k_gather_blocked(
    const int* __restrict__ R, const int* __restrict__ adj,
    const unsigned short* __restrict__ Yb, const float* __restrict__ dis,
    const float* __restrict__ bias, void* __restrict__ Outv, int N)
{
    const int slot = blockIdx.x & 7;
    const int n = (blockIdx.x >> 3) * 128 + (threadIdx.x >> 1);
    const int h = threadIdx.x & 1;          // which 8-dim half of the 16-dim slot
    if (n >= N) return;

    const unsigned short* __restrict__ Ys = Yb + (size_t)slot * N * 16 + h * 8;

    float a[8];
#pragma unroll
    for (int k = 0; k < 8; ++k) a[k] = 0.f;

    // self term (Yb rows already carry the dis[src] factor from the GEMM)
    uint4 sv = *(const uint4*)(Ys + (size_t)n * 16);
    acc_bf8(sv, a);

    int rs = R[n], re = R[n + 1];
    int e = rs;
    for (; e + 4 <= re; e += 4) {
        int s0 = adj[e], s1 = adj[e + 1], s2 = adj[e + 2], s3 = adj[e + 3];
        uint4 v0 = *(const uint4*)(Ys + (size_t)s0 * 16);
        uint4 v1 = *(const uint4*)(Ys + (size_t)s1 * 16);
        uint4 v2 = *(const uint4*)(Ys + (size_t)s2 * 16);
        uint4 v3 = *(const uint4*)(Ys + (size_t)s3 * 16);
        acc_bf8(v0, a); acc_bf8(v1, a); acc_bf8(v2, a); acc_bf8(v3, a);
    }
    for (; e < re; ++e) {
        uint4 v = *(const uint4*)(Ys + (size_t)adj[e] * 16);
        acc_bf8(v, a);
    }

    const float dv = dis[n];
    const int dbase = slot * 16 + h * 8;
    float4 b0 = *(const float4*)(bias + dbase);
    float4 b1 = *(const float4*)(bias + dbase + 4);
    float o[8];
    o[0] = dv * a[0] + b0.x; o[1] = dv * a[1] + b0.y;
    o[2] = dv * a[2] + b0.z; o[3] = dv * a[3] + b0.w;
    o[4] = dv * a[4] + b1.x; o[5] = dv * a[5] + b1.y;
    o[6] = dv * a[6] + b1.z; o[7] = dv * a[7] + b1.w;
    if (RELU) {
#pragma unroll
        for (int k = 0; k < 8; ++k) o[k] = fmaxf(o[k], 0.f);
    }
    if (BF16OUT) {
        // slot-blocked bf16 (feeds layer-2 GEMM): 16B store, coalesced across threads
        uint4 pk;
        pk.x = (unsigned)f2bf(o[0]) | ((unsigned)f2bf(o[1]) << 16);
        pk.y = (unsigned)f2bf(o[2]) | ((unsigned)f2bf(o[3]) << 16);
        pk.z = (unsigned)f2bf(o[4]) | ((unsigned)f2bf(o[5]) << 16);
        pk.w = (unsigned)f2bf(o[6]) | ((unsigned)f2bf(o[7]) << 16);
        *(uint4*)((unsigned short*)Outv + ((size_t)slot * N + n) * 16 + h * 8) = pk;
    } else {
        // final output: row-major f32
        float* op = (float*)Outv + (size_t)n * EMB + dbase;
        float4 q0 = { o[0], o[1], o[2], o[3] };
        float4 q1 = { o[4], o[5], o[6], o[7] };
        *(float4*)op = q0;
        *(float4*)(op + 4) = q1;
    }
}

extern "C" void kernel_launch(void* const* d_in, const int* in_sizes, int n_in,
                              void* d_out, int out_size, void* d_ws, size_t ws_size,
                              hipStream_t stream) {
    const int* ei = (const int*)d_in[0];
    const int E = in_sizes[0] / 2;
    const float* emb = (const float*)d_in[2];
    const int N = in_sizes[2] / EMB;
    const float* W1 = (const float*)d_in[3];
    const float* b1 = (const float*)d_in[4];
    const float* W2 = (const float*)d_in[5];
    const float* b2 = (const float*)d_in[6];
    float* out = (float*)d_out;

    const int* src = ei;
    const int* dstp = ei + E;

    // ws: dis | R | base | tot | adj | W1s | W2s | Hb (part/BH overlay Hb; both
    // dead before gather1 writes Hb).  Y1b lives in d_out bytes (dead before
    // gather2 writes d_out f32).  Total ~33 MB.
    char* w = (char*)d_ws;
    auto take = [&](size_t bytes) { char* p = w; w += (bytes + 511) & ~(size_t)511; return p; };
    float* dis  = (float*)take((size_t)N * 4);
    int*   R    = (int*)  take((size_t)(N + 1) * 4);
    int*   base = (int*)  take((size_t)(NBUC + 1) * 4);
    int*   tot  = (int*)  take((size_t)NBUC * 4);
    int*   adj  = (int*)  take((size_t)E * 4);
    unsigned short* W1s = (unsigned short*)take((size_t)EMB * EMB * 2);
    unsigned short* W2s = (unsigned short*)take((size_t)EMB * EMB * 2);
    unsigned short* Hb  = (unsigned short*)take((size_t)N * EMB * 2);
    int*   part = (int*)Hb;                                  // overlay (dead before Hb)
    int*   BH   = (int*)((char*)Hb + (((size_t)E * 4 + 511) & ~(size_t)511));
    unsigned short* Y1b = (unsigned short*)d_out;            // overlay in d_out

    const int NB = (N + 127) / 128;
    const int chunk = (E + NPART - 1) / NPART;
    const int gM = (N + 63) / 64;            // MFMA gemm blocks
    const int gG = NB * NSLOT;               // 128-node chunks x 8 dim-slots

    // --- CSR + dis build (shared by both layers) ---
    p1_hist   <<<NPART, 256, 0, stream>>>(dstp, BH, E, chunk);
    p_tot     <<<NBUC / 256, 256, 0, stream>>>(BH, tot);
    p_scan    <<<1, NBUC, 0, stream>>>(tot, base, E);
    p_offs    <<<NBUC / 256, 256, 0, stream>>>(BH, base);
    p2_scatter<<<NPART, 256, 0, stream>>>(src, dstp, BH, part, E, chunk);
    p3_csr    <<<NB, 256, 0, stream>>>(part, base, R, adj, dis, N, E);

    // --- weight pre-swizzle (bf16 fragment order) ---
    k_prep_w<<<64, 256, 0, stream>>>(W1, W1s);
    k_prep_w<<<64, 256, 0, stream>>>(W2, W2s);

    // --- layer 1: Y1b = bf16((emb@W1)*dis) blocked; Hb = bf16(relu(...)) blocked ---
    k_gemm_mfma<false><<<gM, 256, 0, stream>>>(emb, W1s, dis, Y1b, N);
    k_gather_blocked<true, true><<<gG, 256, 0, stream>>>(R, adj, Y1b, dis, b1, Hb, N);

    // --- layer 2: Hb = bf16((Hb@W2)*dis) in-place blocked; out = f32 rows ---
    k_gemm_mfma<true><<<gM, 256, 0, stream>>>(Hb, W2s, dis, Hb, N);
    k_gather_blocked<false, false><<<gG, 256, 0, stream>>>(R, adj, Hb, dis, b2, out, N);
}

// Round 2
// 348.831 us; speedup vs baseline: 1.1434x; 1.1434x over previous
//
#include <hip/hip_runtime.h>

#define EMB 128
#define NBUC 1024          // coarse buckets: dst >> 7 (128 nodes per bucket)
#define NPART 256          // partition blocks for P1/P2
#define NSEG 8             // partition segments for the offset scan
#define SEGLEN (NPART / NSEG)   // 32

typedef __attribute__((ext_vector_type(8))) short short8;   // 8 bf16 (4 VGPRs)
typedef __attribute__((ext_vector_type(4))) float f32x4;    // MFMA acc
typedef __attribute__((ext_vector_type(2))) unsigned int uint2v;  // nt-store friendly
typedef __attribute__((ext_vector_type(4))) float float4v;

// ---------------- bf16 helpers ----------------
__device__ __forceinline__ unsigned short f2bf(float f) {
    union { float f; unsigned int i; } v; v.f = f;
    unsigned int x = v.i;
    x += 0x7fffu + ((x >> 16) & 1u);   // round-to-nearest-even
    return (unsigned short)(x >> 16);
}
__device__ __forceinline__ void acc_bf4(uint2 v, float& a0, float& a1, float& a2, float& a3) {
    union { unsigned int i; float f; } t;
    t.i = v.x << 16;          a0 += t.f;
    t.i = v.x & 0xffff0000u;  a1 += t.f;
    t.i = v.y << 16;          a2 += t.f;
    t.i = v.y & 0xffff0000u;  a3 += t.f;
}

// ============ CSR build: atomic-light two-level counting sort ============

__global__ __launch_bounds__(256) void p1_hist(const int* __restrict__ dst,
                                               int* __restrict__ BH, int E, int chunk) {
    __shared__ int h[NBUC];
    for (int i = threadIdx.x; i < NBUC; i += 256) h[i] = 0;
    __syncthreads();
    int s = blockIdx.x * chunk;
    int e = min(E, s + chunk);
    for (int i = s + threadIdx.x; i < e; i += 256)
        atomicAdd(&h[dst[i] >> 7], 1);
    __syncthreads();
    for (int i = threadIdx.x; i < NBUC; i += 256)
        BH[blockIdx.x * NBUC + i] = h[i];
}

// SS[seg][bucket] = sum of BH over the 32 partitions of that segment.
// 32 blocks x 256 threads: serial depth 32 (was 256 in the old p_tot),
// coalesced across threads (consecutive buckets).
__global__ __launch_bounds__(256) void p_segsum(const int* __restrict__ BH,
                                                int* __restrict__ SS) {
    int idx = blockIdx.x * 256 + threadIdx.x;   // 0..8191
    int seg = idx >> 10, b = idx & (NBUC - 1);
    int s = 0;
#pragma unroll 8
    for (int k = 0; k < SEGLEN; ++k)
        s += BH[(seg * SEGLEN + k) * NBUC + b];
    SS[seg * NBUC + b] = s;
}

// Exclusive scan over bucket totals (totals folded in from SS: 8 loads/thread).
__global__ __launch_bounds__(1024) void p_scan(const int* __restrict__ SS,
                                               int* __restrict__ base, int E) {
    __shared__ int a[NBUC];
    int t = threadIdx.x;
    int v0 = 0;
#pragma unroll 8
    for (int s = 0; s < NSEG; ++s) v0 += SS[s * NBUC + t];
    a[t] = v0;
    __syncthreads();
    for (int off = 1; off < NBUC; off <<= 1) {
        int v = (t >= off) ? a[t - off] : 0;
        __syncthreads();
        a[t] += v;
        __syncthreads();
    }
    base[t] = a[t] - v0;
    if (t == NBUC - 1) base[NBUC] = E;
}

// BH[blk][b] <- base[b] + (exclusive running sum over partitions < blk).
// Per (seg,bucket) thread: seg-base from <=7 SS loads, then 32 serial RMWs
// (was 256).  Blocks are seg-uniform -> no divergence on the prefix loop.
__global__ __launch_bounds__(256) void p_offs2(int* __restrict__ BH,
                                               const int* __restrict__ SS,
                                               const int* __restrict__ base) {
    int idx = blockIdx.x * 256 + threadIdx.x;   // 0..8191
    int seg = idx >> 10, b = idx & (NBUC - 1);
    int run = base[b];
    for (int s = 0; s < seg; ++s) run += SS[s * NBUC + b];
#pragma unroll 4
    for (int k = 0; k < SEGLEN; ++k) {
        int* p = &BH[(seg * SEGLEN + k) * NBUC + b];
        int v = *p;
        *p = run;
        run += v;
    }
}

__global__ __launch_bounds__(256) void p2_scatter(const int* __restrict__ src,
                                                  const int* __restrict__ dst,
                                                  const int* __restrict__ BH,
                                                  int* __restrict__ part,
                                                  int E, int chunk) {
    __shared__ int cnt[NBUC];
    for (int i = threadIdx.x; i < NBUC; i += 256)
        cnt[i] = BH[blockIdx.x * NBUC + i];
    __syncthreads();
    int s = blockIdx.x * chunk;
    int e = min(E, s + chunk);
    for (int i = s + threadIdx.x; i < e; i += 256) {
        int d = dst[i];
        int pos = atomicAdd(&cnt[d >> 7], 1);
        part[pos] = src[i] | ((d & 127) << 17);   // src < 2^17, local node in [0,128)
    }
}

__global__ __launch_bounds__(256) void p3_csr(const int* __restrict__ part,
                                              const int* __restrict__ base,
                                              int* __restrict__ R, int* __restrict__ adj,
                                              float* __restrict__ dis, int N, int E) {
    __shared__ int hist[128];
    __shared__ int sc[128];
    __shared__ int cnt[128];
    int b = blockIdx.x;
    int n0 = b * 128;
    int nn = min(128, N - n0);
    int s = base[b], e = base[b + 1];
    int t = threadIdx.x;

    if (t < 128) hist[t] = 0;
    __syncthreads();
    for (int i = s + t; i < e; i += 256)
        atomicAdd(&hist[part[i] >> 17], 1);
    __syncthreads();

    if (t < 128) sc[t] = hist[t];
    __syncthreads();
    for (int off = 1; off < 128; off <<= 1) {
        int v = 0;
        if (t < 128 && t >= off) v = sc[t - off];
        __syncthreads();
        if (t < 128) sc[t] += v;
        __syncthreads();
    }
    if (t < 128) {
        int excl = sc[t] - hist[t];
        cnt[t] = excl;
        if (t < nn) {
            R[n0 + t] = s + excl;
            dis[n0 + t] = rsqrtf((float)hist[t] + 1.0f);   // +1 self-loop
        }
    }
    if (b == 0 && t == 0) R[N] = E;
    __syncthreads();

    for (int i = s + t; i < e; i += 256) {
        int p = part[i];
        int pos = atomicAdd(&cnt[p >> 17], 1);
        adj[s + pos] = p & 0x1FFFF;
    }
}

// ---------------- W pre-swizzle: f32 [128][128] -> bf16 fragment order ----------------
// Wb[kk][ct][q][nn][j] = W[kk*32 + q*8 + j][ct*16 + nn]; lane (q*16+nn) then reads
// its B-frag for (kk,ct) as one contiguous 16B short8 at index (kk*8+ct)*64 + lane.
// Both weight matrices in one launch (blocks 0..63 -> W1, 64..127 -> W2).
__global__ __launch_bounds__(256) void k_prep_w2(const float* __restrict__ W1,
                                                 const float* __restrict__ W2,
                                                 unsigned short* __restrict__ W1s,
                                                 unsigned short* __restrict__ W2s) {
    int gid = blockIdx.x * 256 + threadIdx.x;     // 128 blocks x 256 = 32768
    const float* W = (gid < 16384) ? W1 : W2;
    unsigned short* Ws = (gid < 16384) ? W1s : W2s;
    int idx = gid & 16383;
    int k = idx >> 7, n = idx & 127;
    int kk = k >> 5, q = (k >> 3) & 3, j = k & 7;
    int ct = n >> 4, nn = n & 15;
    int didx = ((((kk * 8 + ct) * 4 + q) * 16 + nn) << 3) + j;
    Ws[didx] = f2bf(W[idx]);
}

// ---------------- MFMA GEMM: Y[n] = bf16((X[n] @ W) * dis[n]) ----------------
// 64 nodes/block, 16/wave; K=128 as 4 steps of mfma_f32_16x16x32_bf16.
// Fragment maps (doc-verified): A: m=lane&15, k=q*8+j; B: n=lane&15, k=q*8+j;
// D: n=lane&15, m=q*4+reg.
// In-place safe for layer 2 (X==Y): a block touches only its own 64 rows; all
// A-frag reads happen in the k-loop, before the __syncthreads() that precedes
// any store.  Epilogue round-trips through LDS for fully-coalesced stores.
template <bool XBF16>
__global__ __launch_bounds__(256) void k_gemm_mfma(
    const void* Xv, const unsigned short* __restrict__ Wsw,
    const float* __restrict__ dis, unsigned short* Y, int N)
{
    __shared__ __align__(16) unsigned short lds[16384];   // 32 KB: W frags, then out-stage

    // stage swizzled W (coalesced 16B copies)
    {
        const uint4* srcp = (const uint4*)Wsw;
        uint4* dstp = (uint4*)lds;
        for (int i = threadIdx.x; i < 2048; i += 256) dstp[i] = srcp[i];
    }
    __syncthreads();

    const int wave = threadIdx.x >> 6;
    const int lane = threadIdx.x & 63;
    const int q = lane >> 4, nn = lane & 15;
    const int row0 = blockIdx.x * 64 + wave * 16;
    const int arow = row0 + nn;
    const int arc = arow < N ? arow : N - 1;

    f32x4 acc[8];
#pragma unroll
    for (int ct = 0; ct < 8; ++ct) acc[ct] = (f32x4){0.f, 0.f, 0.f, 0.f};

#pragma unroll
    for (int kk = 0; kk < 4; ++kk) {
        short8 af;
        if (XBF16) {
            af = *(const short8*)((const unsigned short*)Xv + (size_t)arc * EMB + kk * 32 + q * 8);
        } else {
            const float* xp = (const float*)Xv + (size_t)arc * EMB + kk * 32 + q * 8;
            float4 u0 = *(const float4*)xp;
            float4 u1 = *(const float4*)(xp + 4);
            af[0] = (short)f2bf(u0.x); af[1] = (short)f2bf(u0.y);
            af[2] = (short)f2bf(u0.z); af[3] = (short)f2bf(u0.w);
            af[4] = (short)f2bf(u1.x); af[5] = (short)f2bf(u1.y);
            af[6] = (short)f2bf(u1.z); af[7] = (short)f2bf(u1.w);
        }
#pragma unroll
        for (int ct = 0; ct < 8; ++ct) {
            short8 bf = ((const short8*)lds)[(kk * 8 + ct) * 64 + lane];
            acc[ct] = __builtin_amdgcn_mfma_f32_16x16x32_bf16(af, bf, acc[ct], 0, 0, 0);
        }
    }

    __syncthreads();   // W reads + all A-frag (X) reads complete block-wide

    // scale by dis, pack bf16, stage to LDS (stride 136 shorts = 272B, 16B-aligned)
    float dv[4];
#pragma unroll
    for (int r = 0; r < 4; ++r) {
        int gm = row0 + q * 4 + r;
        dv[r] = dis[gm < N ? gm : N - 1];
    }
#pragma unroll
    for (int ct = 0; ct < 8; ++ct) {
#pragma unroll
        for (int r = 0; r < 4; ++r) {
            int ml = wave * 16 + q * 4 + r;
            lds[ml * 136 + ct * 16 + nn] = f2bf(acc[ct][r] * dv[r]);
        }
    }
    __syncthreads();

    // coalesced store: 64 rows x 256B, 16B per thread-item
    const int rbase = blockIdx.x * 64;
    for (int i = threadIdx.x; i < 1024; i += 256) {
        int row = i >> 4, off = i & 15;
        int grow = rbase + row;
        if (grow < N) {
            uint4 v = *(const uint4*)(lds + row * 136 + off * 8);
            *((uint4*)(Y + (size_t)grow * EMB) + off) = v;
        }
    }
}

// ---------------- fused gather + normalize + bias (+relu) ----------------
// 32 threads/node: a wave's 64 lanes cover 2 nodes reading full contiguous
// 256-B rows (coalesced).  Nontemporal adj loads + output stores keep L2
// capacity for the randomly-reused Y rows (the 55% hit-rate resource).
template <bool RELU, bool BF16OUT>
__global__ __launch_bounds__(256) void k_gather_finalize(
    const int* __restrict__ R, const int* __restrict__ adj,
    const unsigned short* __restrict__ Y, const float* __restrict__ dis,
    const float* __restrict__ bias, void* __restrict__ Outv, int N)
{
    int t = blockIdx.x * 256 + threadIdx.x;
    int n = t >> 5;
    if (n >= N) return;
    int j = (t & 31) * 4;

    int rs = R[n], re = R[n + 1];

    float a0 = 0.f, a1 = 0.f, a2 = 0.f, a3 = 0.f;
    uint2 sv = *(const uint2*)(Y + (size_t)n * EMB + j);
    acc_bf4(sv, a0, a1, a2, a3);

    int e = rs;
    for (; e + 3 < re; e += 4) {
        int s0 = __builtin_nontemporal_load(adj + e);
        int s1 = __builtin_nontemporal_load(adj + e + 1);
        int s2 = __builtin_nontemporal_load(adj + e + 2);
        int s3 = __builtin_nontemporal_load(adj + e + 3);
        uint2 v0 = *(const uint2*)(Y + (size_t)s0 * EMB + j);
        uint2 v1 = *(const uint2*)(Y + (size_t)s1 * EMB + j);
        uint2 v2 = *(const uint2*)(Y + (size_t)s2 * EMB + j);
        uint2 v3 = *(const uint2*)(Y + (size_t)s3 * EMB + j);
        acc_bf4(v0, a0, a1, a2, a3);
        acc_bf4(v1, a0, a1, a2, a3);
        acc_bf4(v2, a0, a1, a2, a3);
        acc_bf4(v3, a0, a1, a2, a3);
    }
    for (; e < re; ++e) {
        int s0 = __builtin_nontemporal_load(adj + e);
        uint2 v0 = *(const uint2*)(Y + (size_t)s0 * EMB + j);
        acc_bf4(v0, a0, a1, a2, a3);
    }

    float dv = dis[n];
    float4 b = *(const float4*)(bias + j);
    float o0 = dv * a0 + b.x;
    float o1 = dv * a1 + b.y;
    float o2 = dv * a2 + b.z;
    float o3 = dv * a3 + b.w;
    if (RELU) {
        o0 = fmaxf(o0, 0.f); o1 = fmaxf(o1, 0.f);
        o2 = fmaxf(o2, 0.f); o3 = fmaxf(o3, 0.f);
    }
    if (BF16OUT) {
        uint2v pk;
        pk.x = (unsigned)f2bf(o0) | ((unsigned)f2bf(o1) << 16);
        pk.y = (unsigned)f2bf(o2) | ((unsigned)f2bf(o3) << 16);
        __builtin_nontemporal_store(pk,
            (uint2v*)((unsigned short*)Outv + (size_t)n * EMB + j));
    } else {
        float4v o = { o0, o1, o2, o3 };
        __builtin_nontemporal_store(o,
            (float4v*)((float*)Outv + (size_t)n * EMB + j));
    }
}

extern "C" void kernel_launch(void* const* d_in, const int* in_sizes, int n_in,
                              void* d_out, int out_size, void* d_ws, size_t ws_size,
                              hipStream_t stream) {
    const int* ei = (const int*)d_in[0];
    const int E = in_sizes[0] / 2;
    const float* emb = (const float*)d_in[2];
    const int N = in_sizes[2] / EMB;
    const float* W1 = (const float*)d_in[3];
    const float* b1 = (const float*)d_in[4];
    const float* W2 = (const float*)d_in[5];
    const float* b2 = (const float*)d_in[6];
    float* out = (float*)d_out;

    const int* src = ei;
    const int* dstp = ei + E;

    // ws: dis | R | base | SS | adj | W1s | W2s | Hb (part/BH overlay Hb; both
    // dead before gather1 writes Hb).  Y1b lives in d_out bytes (dead before
    // gather2 writes d_out f32).  Total ~33 MB.
    char* w = (char*)d_ws;
    auto take = [&](size_t bytes) { char* p = w; w += (bytes + 511) & ~(size_t)511; return p; };
    float* dis  = (float*)take((size_t)N * 4);
    int*   R    = (int*)  take((size_t)(N + 1) * 4);
    int*   base = (int*)  take((size_t)(NBUC + 1) * 4);
    int*   SS   = (int*)  take((size_t)NSEG * NBUC * 4);
    int*   adj  = (int*)  take((size_t)E * 4);
    unsigned short* W1s = (unsigned short*)take((size_t)EMB * EMB * 2);
    unsigned short* W2s = (unsigned short*)take((size_t)EMB * EMB * 2);
    unsigned short* Hb  = (unsigned short*)take((size_t)N * EMB * 2);
    int*   part = (int*)Hb;                                  // overlay (dead before Hb)
    int*   BH   = (int*)((char*)Hb + (((size_t)E * 4 + 511) & ~(size_t)511));
    unsigned short* Y1b = (unsigned short*)d_out;            // overlay in d_out

    const int NB = (N + 127) / 128;
    const int chunk = (E + NPART - 1) / NPART;
    const int gM = (N + 63) / 64;            // MFMA gemm blocks
    const int gG = (N * 32 + 255) / 256;     // gather blocks
    const int gS = (NSEG * NBUC) / 256;      // 32 blocks for segsum/offs

    // --- CSR + dis build (shared by both layers) ---
    p1_hist   <<<NPART, 256, 0, stream>>>(dstp, BH, E, chunk);
    p_segsum  <<<gS, 256, 0, stream>>>(BH, SS);
    p_scan    <<<1, NBUC, 0, stream>>>(SS, base, E);
    p_offs2   <<<gS, 256, 0, stream>>>(BH, SS, base);
    p2_scatter<<<NPART, 256, 0, stream>>>(src, dstp, BH, part, E, chunk);
    p3_csr    <<<NB, 256, 0, stream>>>(part, base, R, adj, dis, N, E);

    // --- weight pre-swizzle (bf16 fragment order), both W in one launch ---
    k_prep_w2<<<128, 256, 0, stream>>>(W1, W2, W1s, W2s);

    // --- layer 1: Y1b = bf16((emb@W1)*dis); Hb = bf16(relu(dis*(gather+self)+b1)) ---
    k_gemm_mfma<false><<<gM, 256, 0, stream>>>(emb, W1s, dis, Y1b, N);
    k_gather_finalize<true, true><<<gG, 256, 0, stream>>>(R, adj, Y1b, dis, b1, Hb, N);

    // --- layer 2: Hb = bf16((Hb@W2)*dis) in-place; out = dis*(gather+self)+b2 ---
    k_gemm_mfma<true><<<gM, 256, 0, stream>>>(Hb, W2s, dis, Hb, N);
    k_gather_finalize<false, false><<<gG, 256, 0, stream>>>(R, adj, Hb, dis, b2, out, N);
}